// Round 3
// baseline (79.550 us; speedup 1.0000x reference)
//
#include <hip/hip_runtime.h>

#define B_ 2
#define N_ 8192
#define K_ 16
#define C_ 64
#define PE_ 32
#define HID_ 16

// ---------------- Kernel 1: ht[b][n][c] = relu(sum_c' W1[c][c'] * f[b][c'][n] + b1[c])
__global__ __launch_bounds__(256) void k1_conv(
    const float* __restrict__ f, const float* __restrict__ W1,
    const float* __restrict__ b1, float* __restrict__ ht) {
  __shared__ float sf[C_ * 64];  // [c][nl]
  const int t = threadIdx.x;
  const int g0 = blockIdx.x * 64;          // flattened b*N + n base
  const int b = g0 >> 13;
  const int n0 = g0 & (N_ - 1);
  for (int idx = t; idx < C_ * 64; idx += 256) {
    int c = idx >> 6, nl = idx & 63;
    sf[c * 64 + nl] = f[(size_t)(b * C_ + c) * N_ + n0 + nl];
  }
  __syncthreads();
  const int nl = t & 63;
  const int q = t >> 6;  // output quarter: oc in [q*16, q*16+16)
  float fv[C_];
  #pragma unroll
  for (int c = 0; c < C_; ++c) fv[c] = sf[c * 64 + nl];
  float* op = ht + (size_t)(g0 + nl) * C_ + q * 16;
  #pragma unroll
  for (int o4 = 0; o4 < 4; ++o4) {
    float r[4];
    #pragma unroll
    for (int u = 0; u < 4; ++u) {
      const int oc = q * 16 + o4 * 4 + u;
      float acc = b1[oc];                  // uniform -> s_load
      #pragma unroll
      for (int c = 0; c < C_; ++c) acc = fmaf(W1[oc * C_ + c], fv[c], acc);
      r[u] = fmaxf(acc, 0.f);
    }
    reinterpret_cast<float4*>(op)[o4] = make_float4(r[0], r[1], r[2], r[3]);
  }
}

// ---------------- Kernel 2: fout[b][c][n] = max_k( pe[b][c][n][k] + ht[b][knn[b][n][k]][c] )
// Block = 256 threads (4 waves), TN=16 points/block -> 1024 blocks, 16 waves/CU.
#define TN 16
__global__ __launch_bounds__(256) void k2_agg(
    const float* __restrict__ pe, const float* __restrict__ ht,
    const int* __restrict__ knn, float* __restrict__ fout) {
  __shared__ float tile[C_ * (TN + 1)];
  const int g0 = blockIdx.x * TN;
  const int b = g0 >> 13;
  const int n0 = g0 & (N_ - 1);
  const int lane = threadIdx.x & 63;       // channel
  const int w = threadIdx.x >> 6;          // wave id 0..3
  #pragma unroll
  for (int j = 0; j < TN / 4; ++j) {
    const int nl = w * (TN / 4) + j;
    const int n = n0 + nl;
    const int* kn = knn + (size_t)(b * N_ + n) * K_;           // uniform -> s_load
    const float4* pe4 =
        reinterpret_cast<const float4*>(pe + ((size_t)(b * C_ + lane) * N_ + n) * K_);
    float4 q0 = pe4[0], q1 = pe4[1], q2 = pe4[2], q3 = pe4[3];
    float pv[16] = {q0.x, q0.y, q0.z, q0.w, q1.x, q1.y, q1.z, q1.w,
                    q2.x, q2.y, q2.z, q2.w, q3.x, q3.y, q3.z, q3.w};
    float acc = -3.402823466e+38f;
    #pragma unroll
    for (int k = 0; k < K_; ++k) {
      const int id = kn[k];
      const float hv = ht[(size_t)(b * N_ + id) * C_ + lane];  // coalesced 256B, L2-hit
      acc = fmaxf(acc, pv[k] + hv);
    }
    tile[lane * (TN + 1) + nl] = acc;
  }
  __syncthreads();
  const int nl2 = threadIdx.x & 15;
  const int c0 = threadIdx.x >> 4;  // 0..15
  #pragma unroll
  for (int r = 0; r < 4; ++r) {
    const int c = c0 + r * 16;
    fout[(size_t)(b * C_ + c) * N_ + n0 + nl2] = tile[c * (TN + 1) + nl2];
  }
}

// ---------------- Kernel 3: KDE offset generator, register-resident rewrite.
// Block = 256 threads = 16 groups of 16 lanes. Phase 2: lane owns d-pair {2l,2l+1};
// phases 1/4/5: lane owns point i. pek transposes through a bank-skewed LDS tile.
#define GRP 16
#define PADD 36                 // spk row stride in floats (16B-aligned, bank-skewed)
#define GSTR (16 * PADD + 8)    // group stride = 584 floats (8g bank rotation)
__global__ __launch_bounds__(256) void k3_kde(
    const float* __restrict__ p, const int* __restrict__ knn,
    const float* __restrict__ Wpe, const float* __restrict__ bpe,
    const float* __restrict__ Wh1, const float* __restrict__ bh1,
    const float* __restrict__ Wh2, const float* __restrict__ bh2,
    float* __restrict__ delta) {
  __shared__ float sc[GRP * 48];        // coords [g][i][3] (192B per group, 16B-aligned)
  __shared__ float spk[GRP * GSTR];     // pek [g][i][d] padded
  const int t = threadIdx.x;
  const int g = t >> 4;
  const int i = t & 15;
  const int gid = blockIdx.x * GRP + g;
  const int b = gid >> 13;

  // ---- phase 1: gather own neighbor coords, share via LDS
  const int idx = knn[(size_t)gid * K_ + i];
  const float* pp = p + (size_t)(b * N_ + idx) * 3;
  const float ci0 = pp[0], ci1 = pp[1], ci2 = pp[2];
  sc[g * 48 + i * 3 + 0] = ci0;
  sc[g * 48 + i * 3 + 1] = ci1;
  sc[g * 48 + i * 3 + 2] = ci2;
  __syncthreads();

  // ---- read all 16 group coords into registers (12 broadcast b128 reads)
  float cx[16], cy[16], cz[16];
  {
    const float4* sq = reinterpret_cast<const float4*>(&sc[g * 48]);
    #pragma unroll
    for (int j4 = 0; j4 < 4; ++j4) {  // 3 float4 = 4 points
      float4 a = sq[j4 * 3 + 0], b4 = sq[j4 * 3 + 1], c4 = sq[j4 * 3 + 2];
      cx[j4 * 4 + 0] = a.x;  cy[j4 * 4 + 0] = a.y;  cz[j4 * 4 + 0] = a.z;
      cx[j4 * 4 + 1] = a.w;  cy[j4 * 4 + 1] = b4.x; cz[j4 * 4 + 1] = b4.y;
      cx[j4 * 4 + 2] = b4.z; cy[j4 * 4 + 2] = b4.w; cz[j4 * 4 + 2] = c4.x;
      cx[j4 * 4 + 3] = c4.y; cy[j4 * 4 + 3] = c4.z; cz[j4 * 4 + 3] = c4.w;
    }
  }

  // ---- phase 2: lane = d-pair owner. proj trick:
  // relu(Wd.(ci-cj)+bd) = relu((Wd.ci+bd) - Wd.cj). All-pairs in registers.
  {
    #pragma unroll
    for (int dd = 0; dd < 2; ++dd) {
      const int d = 2 * i + dd;                 // owned pe-dim (lane-divergent)
      const float wx = Wpe[d * 3 + 0], wy = Wpe[d * 3 + 1], wz = Wpe[d * 3 + 2];
      const float wb = bpe[d];
      float pj[16], aa[16], pk[16];
      #pragma unroll
      for (int j = 0; j < 16; ++j) {
        pj[j] = fmaf(wx, cx[j], fmaf(wy, cy[j], wz * cz[j]));
        aa[j] = pj[j] + wb;
        pk[j] = 0.f;
      }
      #pragma unroll
      for (int j = 0; j < 16; ++j) {
        #pragma unroll
        for (int ii = 0; ii < 16; ++ii)
          pk[ii] += fmaxf(aa[ii] - pj[j], 0.f);
      }
      #pragma unroll
      for (int ii = 0; ii < 16; ++ii)
        spk[g * GSTR + ii * PADD + d] = pk[ii];
    }
  }

  // ---- phase 4 (no sync needed; register-only): kde for own point i
  const float INV2S = 0.49999975f;   // 1/(2*sigma^2 + eps)
  const float COEF = 0.39894225f;    // 1/sqrt(2*pi*sigma^2 + eps)
  float kacc = 0.f;
  #pragma unroll
  for (int j = 0; j < 16; ++j) {
    const float dx = ci0 - cx[j], dy = ci1 - cy[j], dz = ci2 - cz[j];
    kacc += __expf(-(dx * dx + dy * dy + dz * dz) * INV2S);
  }
  const float kde = COEF * kacc;
  float m = kde;
  m = fmaxf(m, __shfl_xor(m, 1));
  m = fmaxf(m, __shfl_xor(m, 2));
  m = fmaxf(m, __shfl_xor(m, 4));
  m = fmaxf(m, __shfl_xor(m, 8));
  const float s = (kde / (m + 1e-6f)) * (1.f / 16.f);  // kdn * mean(1/16)

  __syncthreads();

  // ---- phase 5: lane = point i. Read own pek row (b128 x8), MLP with SGPR weights.
  float pek[PE_];
  {
    const float4* pk4 = reinterpret_cast<const float4*>(&spk[g * GSTR + i * PADD]);
    #pragma unroll
    for (int k = 0; k < 8; ++k) {
      float4 v = pk4[k];
      pek[4 * k + 0] = v.x * s;
      pek[4 * k + 1] = v.y * s;
      pek[4 * k + 2] = v.z * s;
      pek[4 * k + 3] = v.w * s;
    }
  }
  float o0 = bh2[0], o1 = bh2[1], o2 = bh2[2];
  #pragma unroll
  for (int h = 0; h < HID_; ++h) {
    float a = bh1[h];
    #pragma unroll
    for (int d = 0; d < PE_; ++d) a = fmaf(Wh1[h * PE_ + d], pek[d], a);  // uniform -> s_load
    a = fmaxf(a, 0.f);
    o0 = fmaf(Wh2[0 * HID_ + h], a, o0);
    o1 = fmaf(Wh2[1 * HID_ + h], a, o1);
    o2 = fmaf(Wh2[2 * HID_ + h], a, o2);
  }
  float* dp = delta + ((size_t)gid * K_ + i) * 3;
  dp[0] = o0;
  dp[1] = o1;
  dp[2] = o2;
}

extern "C" void kernel_launch(void* const* d_in, const int* in_sizes, int n_in,
                              void* d_out, int out_size, void* d_ws, size_t ws_size,
                              hipStream_t stream) {
  // setup_inputs() dict order: p, f, pe, W1, b1, Wpe, bpe, Wh1, bh1, Wh2, bh2, knn_idx
  const float* p   = (const float*)d_in[0];
  const float* f   = (const float*)d_in[1];
  const float* pe  = (const float*)d_in[2];
  const float* W1  = (const float*)d_in[3];
  const float* b1  = (const float*)d_in[4];
  const float* Wpe = (const float*)d_in[5];
  const float* bpe = (const float*)d_in[6];
  const float* Wh1 = (const float*)d_in[7];
  const float* bh1 = (const float*)d_in[8];
  const float* Wh2 = (const float*)d_in[9];
  const float* bh2 = (const float*)d_in[10];
  const int* knn   = (const int*)d_in[11];
  float* fout  = (float*)d_out;                        // [B,C,N]
  float* delta = (float*)d_out + (size_t)B_ * C_ * N_; // [B*N,K,3]
  float* ht = (float*)d_ws;                            // [B,N,C] = 4 MB scratch

  k1_conv<<<(B_ * N_) / 64, 256, 0, stream>>>(f, W1, b1, ht);
  k2_agg<<<(B_ * N_) / TN, 256, 0, stream>>>(pe, ht, knn, fout);
  k3_kde<<<(B_ * N_) / GRP, 256, 0, stream>>>(p, knn, Wpe, bpe, Wh1, bh1, Wh2, bh2, delta);
}

// Round 4
// 76.403 us; speedup vs baseline: 1.0412x; 1.0412x over previous
//
#include <hip/hip_runtime.h>

#define B_ 2
#define N_ 8192
#define K_ 16
#define C_ 64
#define PE_ 32
#define HID_ 16

typedef float f4 __attribute__((ext_vector_type(4)));

// ---------------- Kernel 1: ht[b][n][c] = relu(sum_c' W1[c][c'] * f[b][c'][n] + b1[c])
__global__ __launch_bounds__(256) void k1_conv(
    const float* __restrict__ f, const float* __restrict__ W1,
    const float* __restrict__ b1, float* __restrict__ ht) {
  __shared__ float sf[C_ * 64];  // [c][nl]
  const int t = threadIdx.x;
  const int g0 = blockIdx.x * 64;          // flattened b*N + n base
  const int b = g0 >> 13;
  const int n0 = g0 & (N_ - 1);
  for (int idx = t; idx < C_ * 64; idx += 256) {
    int c = idx >> 6, nl = idx & 63;
    sf[c * 64 + nl] = __builtin_nontemporal_load(&f[(size_t)(b * C_ + c) * N_ + n0 + nl]);
  }
  __syncthreads();
  const int nl = t & 63;
  const int q = t >> 6;  // output quarter: oc in [q*16, q*16+16)
  float fv[C_];
  #pragma unroll
  for (int c = 0; c < C_; ++c) fv[c] = sf[c * 64 + nl];
  float* op = ht + (size_t)(g0 + nl) * C_ + q * 16;
  #pragma unroll
  for (int o4 = 0; o4 < 4; ++o4) {
    float r[4];
    #pragma unroll
    for (int u = 0; u < 4; ++u) {
      const int oc = q * 16 + o4 * 4 + u;
      float acc = b1[oc];                  // wave-uniform -> s_load
      #pragma unroll
      for (int c = 0; c < C_; ++c) acc = fmaf(W1[oc * C_ + c], fv[c], acc);
      r[u] = fmaxf(acc, 0.f);
    }
    reinterpret_cast<float4*>(op)[o4] = make_float4(r[0], r[1], r[2], r[3]);
  }
}

// ---------------- Kernel 2 (redesigned): fout[b][c][n] = max_k( pe[b][c][n][k] + ht[knn[n][k]][c] )
// TNB=8 points/block. Phase A: lane=c gathers into swizzled LDS. Phase B: lane=(n,k),
// pe read fully coalesced (2 c-rows x 512B contiguous per wave-inst), nontemporal.
#define TNB 8
__global__ __launch_bounds__(256) void k2_agg(
    const float* __restrict__ pe, const float* __restrict__ ht,
    const int* __restrict__ knn, float* __restrict__ fout) {
  __shared__ float sfj[C_ * 128];   // [c][swizzled nk], 32 KB
  __shared__ float sout[C_ * 10];   // [c][n] pad 10 (8B-aligned rows, bank-skewed)
  const int g0 = blockIdx.x * TNB;
  const int b = g0 >> 13;
  const int n0 = g0 & (N_ - 1);
  const int lane = threadIdx.x & 63;
  const int w = threadIdx.x >> 6;        // wave 0..3 owns k in [w*4, w*4+4)
  const int swz = lane & 31;
  const int wele = (lane >> 3) & 3;      // element-level bank skew
  // ---- Phase A: gather fj -> LDS. ht rows are 256B coalesced, L2-resident.
  #pragma unroll
  for (int n = 0; n < TNB; ++n) {
    const int* kn = knn + (size_t)(b * N_ + n0 + n) * K_ + w * 4;
    #pragma unroll
    for (int kk = 0; kk < 4; ++kk) {
      const int id = kn[kk];
      const float hv = ht[(size_t)(b * N_ + id) * C_ + lane];
      // quad index nk4 = n*4+w (k>>2 == w), element kk; both XOR-skewed
      sfj[lane * 128 + (((n * 4 + w) ^ swz) << 2) + (kk ^ wele)] = hv;
    }
  }
  __syncthreads();
  // ---- Phase B: wave covers 2 c-rows/iter. h=row half, sl=quad, n=sl>>2, j=sl&3.
  const int h = lane >> 5, sl = lane & 31;
  const int n = sl >> 2, j = sl & 3;
  #pragma unroll
  for (int it = 0; it < 8; ++it) {
    const int c = it * 8 + w * 2 + h;
    const int px = it & 3;               // compile-time elem un-permute ((c>>3)&3 == it&3)
    const f4 pv = __builtin_nontemporal_load(
        reinterpret_cast<const f4*>(pe + ((size_t)(b * C_ + c) * N_ + n0) * K_) + sl);
    const f4 fj = *reinterpret_cast<const f4*>(&sfj[c * 128 + ((sl ^ (c & 31)) << 2)]);
    float v = fmaxf(fmaxf(pv[0] + fj[0 ^ px], pv[1] + fj[1 ^ px]),
                    fmaxf(pv[2] + fj[2 ^ px], pv[3] + fj[3 ^ px]));
    v = fmaxf(v, __shfl_xor(v, 1));      // combine k-quads j^1
    v = fmaxf(v, __shfl_xor(v, 2));      // combine k-quads j^2
    if (j == 0) sout[c * 10 + n] = v;
  }
  __syncthreads();
  // ---- coalesced fout write: thread t -> c = t>>2, 2 n's (plain store, L2 merges)
  const int t = threadIdx.x;
  const int c = t >> 2, q = t & 3;
  const float2 r = *reinterpret_cast<const float2*>(&sout[c * 10 + q * 2]);
  *reinterpret_cast<float2*>(fout + (size_t)(b * C_ + c) * N_ + n0 + q * 2) = r;
}

// ---------------- Kernel 3: KDE offset generator, register-resident (unchanged from R3).
#define GRP 16
#define PADD 36
#define GSTR (16 * PADD + 8)
__global__ __launch_bounds__(256) void k3_kde(
    const float* __restrict__ p, const int* __restrict__ knn,
    const float* __restrict__ Wpe, const float* __restrict__ bpe,
    const float* __restrict__ Wh1, const float* __restrict__ bh1,
    const float* __restrict__ Wh2, const float* __restrict__ bh2,
    float* __restrict__ delta) {
  __shared__ float sc[GRP * 48];
  __shared__ float spk[GRP * GSTR];
  const int t = threadIdx.x;
  const int g = t >> 4;
  const int i = t & 15;
  const int gid = blockIdx.x * GRP + g;
  const int b = gid >> 13;

  const int idx = knn[(size_t)gid * K_ + i];
  const float* pp = p + (size_t)(b * N_ + idx) * 3;
  const float ci0 = pp[0], ci1 = pp[1], ci2 = pp[2];
  sc[g * 48 + i * 3 + 0] = ci0;
  sc[g * 48 + i * 3 + 1] = ci1;
  sc[g * 48 + i * 3 + 2] = ci2;
  __syncthreads();

  float cx[16], cy[16], cz[16];
  {
    const float4* sq = reinterpret_cast<const float4*>(&sc[g * 48]);
    #pragma unroll
    for (int j4 = 0; j4 < 4; ++j4) {
      float4 a = sq[j4 * 3 + 0], b4 = sq[j4 * 3 + 1], c4 = sq[j4 * 3 + 2];
      cx[j4 * 4 + 0] = a.x;  cy[j4 * 4 + 0] = a.y;  cz[j4 * 4 + 0] = a.z;
      cx[j4 * 4 + 1] = a.w;  cy[j4 * 4 + 1] = b4.x; cz[j4 * 4 + 1] = b4.y;
      cx[j4 * 4 + 2] = b4.z; cy[j4 * 4 + 2] = b4.w; cz[j4 * 4 + 2] = c4.x;
      cx[j4 * 4 + 3] = c4.y; cy[j4 * 4 + 3] = c4.z; cz[j4 * 4 + 3] = c4.w;
    }
  }

  // proj trick: relu(Wd.(ci-cj)+bd) = relu((Wd.ci+bd) - Wd.cj); all-pairs in regs
  {
    #pragma unroll
    for (int dd = 0; dd < 2; ++dd) {
      const int d = 2 * i + dd;
      const float wx = Wpe[d * 3 + 0], wy = Wpe[d * 3 + 1], wz = Wpe[d * 3 + 2];
      const float wb = bpe[d];
      float pj[16], aa[16], pk[16];
      #pragma unroll
      for (int j = 0; j < 16; ++j) {
        pj[j] = fmaf(wx, cx[j], fmaf(wy, cy[j], wz * cz[j]));
        aa[j] = pj[j] + wb;
        pk[j] = 0.f;
      }
      #pragma unroll
      for (int j = 0; j < 16; ++j) {
        #pragma unroll
        for (int ii = 0; ii < 16; ++ii)
          pk[ii] += fmaxf(aa[ii] - pj[j], 0.f);
      }
      #pragma unroll
      for (int ii = 0; ii < 16; ++ii)
        spk[g * GSTR + ii * PADD + d] = pk[ii];
    }
  }

  const float INV2S = 0.49999975f;
  const float COEF = 0.39894225f;
  float kacc = 0.f;
  #pragma unroll
  for (int j = 0; j < 16; ++j) {
    const float dx = ci0 - cx[j], dy = ci1 - cy[j], dz = ci2 - cz[j];
    kacc += __expf(-(dx * dx + dy * dy + dz * dz) * INV2S);
  }
  const float kde = COEF * kacc;
  float m = kde;
  m = fmaxf(m, __shfl_xor(m, 1));
  m = fmaxf(m, __shfl_xor(m, 2));
  m = fmaxf(m, __shfl_xor(m, 4));
  m = fmaxf(m, __shfl_xor(m, 8));
  const float s = (kde / (m + 1e-6f)) * (1.f / 16.f);

  __syncthreads();

  float pek[PE_];
  {
    const float4* pk4 = reinterpret_cast<const float4*>(&spk[g * GSTR + i * PADD]);
    #pragma unroll
    for (int k = 0; k < 8; ++k) {
      float4 v = pk4[k];
      pek[4 * k + 0] = v.x * s;
      pek[4 * k + 1] = v.y * s;
      pek[4 * k + 2] = v.z * s;
      pek[4 * k + 3] = v.w * s;
    }
  }
  float o0 = bh2[0], o1 = bh2[1], o2 = bh2[2];
  #pragma unroll
  for (int hh = 0; hh < HID_; ++hh) {
    float a = bh1[hh];
    #pragma unroll
    for (int d = 0; d < PE_; ++d) a = fmaf(Wh1[hh * PE_ + d], pek[d], a);
    a = fmaxf(a, 0.f);
    o0 = fmaf(Wh2[0 * HID_ + hh], a, o0);
    o1 = fmaf(Wh2[1 * HID_ + hh], a, o1);
    o2 = fmaf(Wh2[2 * HID_ + hh], a, o2);
  }
  float* dp = delta + ((size_t)gid * K_ + i) * 3;
  dp[0] = o0;
  dp[1] = o1;
  dp[2] = o2;
}

extern "C" void kernel_launch(void* const* d_in, const int* in_sizes, int n_in,
                              void* d_out, int out_size, void* d_ws, size_t ws_size,
                              hipStream_t stream) {
  // setup_inputs() dict order: p, f, pe, W1, b1, Wpe, bpe, Wh1, bh1, Wh2, bh2, knn_idx
  const float* p   = (const float*)d_in[0];
  const float* f   = (const float*)d_in[1];
  const float* pe  = (const float*)d_in[2];
  const float* W1  = (const float*)d_in[3];
  const float* b1  = (const float*)d_in[4];
  const float* Wpe = (const float*)d_in[5];
  const float* bpe = (const float*)d_in[6];
  const float* Wh1 = (const float*)d_in[7];
  const float* bh1 = (const float*)d_in[8];
  const float* Wh2 = (const float*)d_in[9];
  const float* bh2 = (const float*)d_in[10];
  const int* knn   = (const int*)d_in[11];
  float* fout  = (float*)d_out;                        // [B,C,N]
  float* delta = (float*)d_out + (size_t)B_ * C_ * N_; // [B*N,K,3]
  float* ht = (float*)d_ws;                            // [B,N,C] = 4 MB scratch

  k1_conv<<<(B_ * N_) / 64, 256, 0, stream>>>(f, W1, b1, ht);
  k2_agg<<<(B_ * N_) / TNB, 256, 0, stream>>>(pe, ht, knn, fout);
  k3_kde<<<(B_ * N_) / GRP, 256, 0, stream>>>(p, knn, Wpe, bpe, Wh1, bh1, Wh2, bh2, delta);
}